// Round 10
// baseline (1533.183 us; speedup 1.0000x reference)
//
#include <hip/hip_runtime.h>

#define DEVI __device__ __forceinline__

typedef float  f32x4  __attribute__((ext_vector_type(4)));
typedef __bf16 bf16x8 __attribute__((ext_vector_type(8)));
typedef unsigned short u16x8 __attribute__((ext_vector_type(8)));

// ---------- helpers ----------
DEVI unsigned short f2bf(float f) {
    unsigned u = __builtin_bit_cast(unsigned, f);
    unsigned r = (u + 0x7fffu + ((u >> 16) & 1u)) >> 16;
    return (unsigned short)r;
}
DEVI float bf2f(unsigned short s) {
    return __builtin_bit_cast(float, (unsigned)s << 16);
}
DEVI u16x8 pack8(float4 a, float4 b) {
    u16x8 p;
    p[0] = f2bf(a.x); p[1] = f2bf(a.y); p[2] = f2bf(a.z); p[3] = f2bf(a.w);
    p[4] = f2bf(b.x); p[5] = f2bf(b.y); p[6] = f2bf(b.z); p[7] = f2bf(b.w);
    return p;
}
DEVI f32x4 mfma16(u16x8 a, u16x8 b, f32x4 c) {
    return __builtin_amdgcn_mfma_f32_16x16x32_bf16(
        __builtin_bit_cast(bf16x8, a), __builtin_bit_cast(bf16x8, b), c, 0, 0, 0);
}
DEVI float sigm(float x)   { return 1.f / (1.f + __expf(-x)); }
DEVI float tanh_f(float x) { return 1.f - 2.f / (1.f + __expf(2.f * x)); }

// dims
#define Hh 256
#define Bb 64
#define Tt 1024
#define MROWS (Bb * Tt)   // 65536

// ---------- K0: hp[b][k] = sum_h hidden[b][h] * W_w[k][h] (first H cols) ----------
__global__ __launch_bounds__(256) void hp_kernel(const float* __restrict__ hid,
                                                 const float* __restrict__ Ww,
                                                 float* __restrict__ hp) {
    int b = blockIdx.x, k = threadIdx.x;
    __shared__ __align__(16) float hs[Hh];
    hs[k] = hid[b * Hh + k];
    __syncthreads();
    const float4* w4 = (const float4*)(Ww + (size_t)k * 512);
    const float4* h4 = (const float4*)hs;
    float acc = 0.f;
#pragma unroll 8
    for (int i = 0; i < 64; i++) {
        float4 a = w4[i], x = h4[i];
        acc += a.x * x.x + a.y * x.y + a.z * x.z + a.w * x.w;
    }
    hp[b * Hh + k] = acc;
}

// ---------- bias prep: cb[0][k]=b_ir+b_hr, cb[1][k]=b_iz+b_hz ----------
__global__ __launch_bounds__(256) void bias_prep(const float* __restrict__ b_ir,
                                                 const float* __restrict__ b_hr,
                                                 const float* __restrict__ b_iz,
                                                 const float* __restrict__ b_hz,
                                                 float* __restrict__ cb) {
    int k = threadIdx.x;
    cb[k] = b_ir[k] + b_hr[k];
    cb[256 + k] = b_iz[k] + b_hz[k];
}

// ---------- GEMM: OUT = epilogue( A(65536x256) @ W^T )  BM=128 BN=64 K=256 ----------
// EPI 0: z = tanh(acc + hp[b][c] + W_b[c]) -> bf16 [r][c]
// EPI 1: scores = acc + V_b[c]            -> f32  [r][c]
// EPI 2: xproj  = acc + b_i[c]            -> bf16 [mat][t][b][c]
template <int EPI, bool ABF16>
__global__ __launch_bounds__(512) void gemm_k(
    const void* __restrict__ Aab,
    const float* __restrict__ W0, const float* __restrict__ W1, const float* __restrict__ W2,
    int wstride, int wcoloff,
    const float* __restrict__ bv0, const float* __restrict__ bv1, const float* __restrict__ bv2,
    const float* __restrict__ hp, const float* __restrict__ Wb,
    void* __restrict__ outv) {
    __shared__ __align__(16) unsigned short As[128 * 256];
    __shared__ __align__(16) unsigned short Bs[64 * 256];

    int tid = threadIdx.x;
    int bx = blockIdx.x, by = blockIdx.y;
    int mat = (EPI == 2) ? (by >> 2) : 0;
    int cb  = (EPI == 2) ? (by & 3) : by;
    int rowBase = bx * 128, colBase = cb * 64;
    const float* W  = (mat == 0) ? W0 : ((mat == 1) ? W1 : W2);
    const float* bv = (mat == 0) ? bv0 : ((mat == 1) ? bv1 : bv2);

    // stage A: 128 rows x 32 chunks(16B), swizzled g ^= (r&7)
    if (ABF16) {
        const unsigned short* A = (const unsigned short*)Aab;
#pragma unroll
        for (int i = 0; i < 8; i++) {
            int idx = i * 512 + tid, r = idx >> 5, g = idx & 31, gs = g ^ (r & 7);
            *(uint4*)&As[r * 256 + gs * 8] =
                *(const uint4*)(A + (((size_t)(rowBase + r)) << 8) + g * 8);
        }
    } else {
        const float* A = (const float*)Aab;
#pragma unroll
        for (int i = 0; i < 8; i++) {
            int idx = i * 512 + tid, r = idx >> 5, g = idx & 31, gs = g ^ (r & 7);
            const float* s = A + (((size_t)(rowBase + r)) << 8) + g * 8;
            float4 f0 = *(const float4*)s, f1 = *(const float4*)(s + 4);
            *(u16x8*)&As[r * 256 + gs * 8] = pack8(f0, f1);
        }
    }
    // stage B: 64 W-rows (output cols) x 32 chunks
#pragma unroll
    for (int i = 0; i < 4; i++) {
        int idx = i * 512 + tid, r = idx >> 5, g = idx & 31, gs = g ^ (r & 7);
        const float* s = W + (size_t)(colBase + r) * wstride + wcoloff + g * 8;
        float4 f0 = *(const float4*)s, f1 = *(const float4*)(s + 4);
        *(u16x8*)&Bs[r * 256 + gs * 8] = pack8(f0, f1);
    }
    __syncthreads();

    int wid = tid >> 6, lane = tid & 63, l15 = lane & 15, grp = lane >> 4;
    int wr = (wid >> 1) * 32, wc = (wid & 1) * 32;
    f32x4 acc[2][2] = {};
#pragma unroll
    for (int kc = 0; kc < 8; kc++) {
        u16x8 a[2], bb[2];
#pragma unroll
        for (int rt = 0; rt < 2; rt++) {
            int r = wr + rt * 16 + l15;
            int gs = (kc * 4 + grp) ^ (r & 7);
            a[rt] = *(const u16x8*)&As[r * 256 + gs * 8];
        }
#pragma unroll
        for (int ct = 0; ct < 2; ct++) {
            int r = wc + ct * 16 + l15;
            int gs = (kc * 4 + grp) ^ (r & 7);
            bb[ct] = *(const u16x8*)&Bs[r * 256 + gs * 8];
        }
#pragma unroll
        for (int rt = 0; rt < 2; rt++)
#pragma unroll
            for (int ct = 0; ct < 2; ct++)
                acc[rt][ct] = mfma16(a[rt], bb[ct], acc[rt][ct]);
    }
    // epilogue: D row = (lane>>4)*4 + i, col = lane&15
#pragma unroll
    for (int rt = 0; rt < 2; rt++)
#pragma unroll
        for (int ct = 0; ct < 2; ct++)
#pragma unroll
            for (int i = 0; i < 4; i++) {
                int rl = wr + rt * 16 + grp * 4 + i;
                int cl = wc + ct * 16 + l15;
                size_t r = (size_t)rowBase + rl;
                int c = colBase + cl;
                float v = acc[rt][ct][i];
                if (EPI == 0) {
                    v = tanh_f(v + hp[(r >> 10) * 256 + c] + Wb[c]);
                    ((unsigned short*)outv)[r * 256 + c] = f2bf(v);
                } else if (EPI == 1) {
                    ((float*)outv)[r * 256 + c] = v + bv[c];
                } else {
                    size_t t = r & 1023, b = r >> 10;
                    ((unsigned short*)outv)[(size_t)mat * 16777216 + (t * 64 + b) * 256 + c] =
                        f2bf(v + bv[c]);
                }
            }
}

// ---------- softmax over T, pass 1: per (b,k) online max/sumexp over a T-chunk ----------
__global__ __launch_bounds__(256) void softmax_pass1(const float* __restrict__ scores,
                                                     float* __restrict__ partMS) {
    int b = blockIdx.x, tc = blockIdx.y, k = threadIdx.x;
    const float* p = scores + ((size_t)b * Tt + tc * 128) * Hh + k;
    float m = -1e30f, S = 0.f;
    for (int i = 0; i < 128; i++) {
        float s = p[(size_t)i * Hh];
        float mn = fmaxf(m, s);
        S = S * __expf(m - mn) + __expf(s - mn);
        m = mn;
    }
    int idx = (b * 8 + tc) * Hh + k;
    partMS[idx * 2] = m;
    partMS[idx * 2 + 1] = S;
}

// ---------- softmax pass 2: combine partials, emit ctx (bf16) and x_attn ----------
__global__ __launch_bounds__(256) void softmax_pass2(const float* __restrict__ scores,
                                                     const float* __restrict__ partMS,
                                                     unsigned short* __restrict__ ctx,
                                                     float* __restrict__ x_attn) {
    int b = blockIdx.x, tc = blockIdx.y;
    int tid = threadIdx.x, w = tid >> 6, lane = tid & 63;
    float mj[4], Sj[4];
#pragma unroll
    for (int j = 0; j < 4; j++) {
        int k = lane + j * 64;
        float m = -1e30f;
#pragma unroll
        for (int c = 0; c < 8; c++)
            m = fmaxf(m, partMS[((b * 8 + c) * Hh + k) * 2]);
        float S = 0.f;
#pragma unroll
        for (int c = 0; c < 8; c++) {
            int idx = (b * 8 + c) * Hh + k;
            S += partMS[idx * 2 + 1] * __expf(partMS[idx * 2] - m);
        }
        mj[j] = m;
        Sj[j] = 1.f / S;
    }
    for (int i = 0; i < 32; i++) {
        int t = tc * 128 + w * 32 + i;
        const float* sp = scores + ((size_t)b * Tt + t) * Hh;
        unsigned short* cp = ctx + ((size_t)b * Tt + t) * Hh;
        float accsm = 0.f;
#pragma unroll
        for (int j = 0; j < 4; j++) {
            int k = lane + j * 64;
            float s = sp[k];
            float sm = __expf(s - mj[j]) * Sj[j];
            accsm += sm;
            cp[k] = f2bf(s * sm);
        }
#pragma unroll
        for (int o = 32; o >= 1; o >>= 1) accsm += __shfl_xor(accsm, o, 64);
        if (lane == 0) x_attn[b * Tt + t] = accsm;
    }
}

// ---------- GRU scan ----------
// R9 post-mortem: conflicts 3.35e7->0, 1408->1248us. Remaining 2930cy/step =
// 1862 MFMA-issue floor + ~400 tail + ~650 from wn_lds streaming (128KB/step
// = 512cy of LDS BW + 16 ds_read slots in the MFMA stream) and clock droop.
// R8/R9 counters prove the per-wave budget is NOT 256: arch 128 + 152 AGPR
// ran fine (pool 2048/SIMD, 2 waves/SIMD). R10: ALL THREE matrices in AGPR
// (192 wf + 24 acc = 216 AGPR + ~80 arch ~= 296/wave, 592/SIMD -- fits).
// No per-step LDS weight traffic at all. Keep the 112KB LDS pad: it forces
// the 1-WG/CU occupancy target that makes the allocator grant the AGPRs
// (proven load-bearing R5->R8). Batch all 8 hb reads post-barrier.
#define HBPAD 28672  // u16 elems per buffer; 2*28672*2B = 112 KB LDS (1 WG/CU)
__global__ __attribute__((amdgpu_flat_work_group_size(512, 512),
                          amdgpu_waves_per_eu(2, 2)))
void scan_gru(
    const unsigned short* __restrict__ xg,
    const float* __restrict__ whr, const float* __restrict__ whz, const float* __restrict__ whn,
    const float* __restrict__ bhn,
    const float* __restrict__ hidden,
    float* __restrict__ outputs, float* __restrict__ hlast) {
    __shared__ __align__(16) unsigned short hb[2][HBPAD];  // h dbuf in first 256; rest = occupancy limiter
    int b = blockIdx.x;
    int tid = threadIdx.x, w = tid >> 6, lane = tid & 63;
    int grp = lane >> 4;

    // weight fragments: wave owns cols [32w,32w+32) of all 3 matrices,
    // 2 col-tiles x 8 K-chunks each
    u16x8 wfr[2][8], wfz[2][8], wfn[2][8];
#pragma unroll
    for (int ct = 0; ct < 2; ct++) {
        int col = w * 32 + ct * 16 + (lane & 15);
#pragma unroll
        for (int kc = 0; kc < 8; kc++) {
            const float* s1 = whr + (size_t)col * Hh + kc * 32 + grp * 8;
            wfr[ct][kc] = pack8(*(const float4*)s1, *(const float4*)(s1 + 4));
            const float* s2 = whz + (size_t)col * Hh + kc * 32 + grp * 8;
            wfz[ct][kc] = pack8(*(const float4*)s2, *(const float4*)(s2 + 4));
            const float* s3 = whn + (size_t)col * Hh + kc * 32 + grp * 8;
            wfn[ct][kc] = pack8(*(const float4*)s3, *(const float4*)(s3 + 4));
        }
    }
    // Coax all 48 fragments (192 regs) into the AGPR half of the unified RF
    // (value-preserving empty asm; R8/R9 verified this kills the spill).
    asm volatile("" : "+a"(wfr[0][0]), "+a"(wfr[0][1]), "+a"(wfr[0][2]), "+a"(wfr[0][3]),
                      "+a"(wfr[0][4]), "+a"(wfr[0][5]), "+a"(wfr[0][6]), "+a"(wfr[0][7]));
    asm volatile("" : "+a"(wfr[1][0]), "+a"(wfr[1][1]), "+a"(wfr[1][2]), "+a"(wfr[1][3]),
                      "+a"(wfr[1][4]), "+a"(wfr[1][5]), "+a"(wfr[1][6]), "+a"(wfr[1][7]));
    asm volatile("" : "+a"(wfz[0][0]), "+a"(wfz[0][1]), "+a"(wfz[0][2]), "+a"(wfz[0][3]),
                      "+a"(wfz[0][4]), "+a"(wfz[0][5]), "+a"(wfz[0][6]), "+a"(wfz[0][7]));
    asm volatile("" : "+a"(wfz[1][0]), "+a"(wfz[1][1]), "+a"(wfz[1][2]), "+a"(wfz[1][3]),
                      "+a"(wfz[1][4]), "+a"(wfz[1][5]), "+a"(wfz[1][6]), "+a"(wfz[1][7]));
    asm volatile("" : "+a"(wfn[0][0]), "+a"(wfn[0][1]), "+a"(wfn[0][2]), "+a"(wfn[0][3]),
                      "+a"(wfn[0][4]), "+a"(wfn[0][5]), "+a"(wfn[0][6]), "+a"(wfn[0][7]));
    asm volatile("" : "+a"(wfn[1][0]), "+a"(wfn[1][1]), "+a"(wfn[1][2]), "+a"(wfn[1][3]),
                      "+a"(wfn[1][4]), "+a"(wfn[1][5]), "+a"(wfn[1][6]), "+a"(wfn[1][7]));

    // per-lane state: lanes 0-15 own col0 block, lanes 16-31 own col1 block
    int mycol = w * 32 + (lane & 31);
    float bhnS = 0.f, hpS = 0.f;
    if (lane < 32) {
        bhnS = bhn[mycol];
        hpS = hidden[b * Hh + mycol];
        hb[0][mycol] = f2bf(hpS);
        outputs[((size_t)b * Tt) * Hh + mycol] = hpS;  // outputs[:,0,:] = h0 exact
    }
    const unsigned short* xr = xg;
    const unsigned short* xz = xg + 16777216;
    const unsigned short* xn = xg + 33554432;
    unsigned short pxr = 0, pxz = 0, pxn = 0;
    if (lane < 32) {
        size_t off = ((size_t)64 + b) * Hh + mycol;  // t=1
        pxr = xr[off]; pxz = xz[off]; pxn = xn[off];
    }
    __syncthreads();

    int p = 0;
    for (int t = 1; t < Tt; t++) {
        unsigned short cxr = pxr, cxz = pxz, cxn = pxn;
        int tnext = (t + 1 < Tt) ? t + 1 : t;
        if (lane < 32) {  // prefetch next step (latency hidden under MFMAs)
            size_t off = ((size_t)tnext * 64 + b) * Hh + mycol;
            pxr = xr[off]; pxz = xz[off]; pxn = xn[off];
        }
        // batch all 8 broadcast reads of h so lgkmcnt overlaps the MFMA stream
        u16x8 af[8];
#pragma unroll
        for (int kc = 0; kc < 8; kc++)
            af[kc] = *(const u16x8*)&hb[p][kc * 32 + grp * 8];
        f32x4 ar0 = {0.f, 0.f, 0.f, 0.f}, ar1 = {0.f, 0.f, 0.f, 0.f};
        f32x4 az0 = {0.f, 0.f, 0.f, 0.f}, az1 = {0.f, 0.f, 0.f, 0.f};
        f32x4 an0 = {0.f, 0.f, 0.f, 0.f}, an1 = {0.f, 0.f, 0.f, 0.f};
#pragma unroll
        for (int kc = 0; kc < 8; kc++) {
            ar0 = mfma16(af[kc], wfr[0][kc], ar0);
            ar1 = mfma16(af[kc], wfr[1][kc], ar1);
            az0 = mfma16(af[kc], wfz[0][kc], az0);
            az1 = mfma16(af[kc], wfz[1][kc], az1);
            an0 = mfma16(af[kc], wfn[0][kc], an0);
            an1 = mfma16(af[kc], wfn[1][kc], an1);
        }
        // move col1-block accs (row 0 lives in lanes 0-15) to lanes 16-31
        float vr = __shfl(ar1[0], lane & 15);
        float vz = __shfl(az1[0], lane & 15);
        float vn = __shfl(an1[0], lane & 15);
        float gr = (lane < 16) ? ar0[0] : vr;
        float gz = (lane < 16) ? az0[0] : vz;
        float gn = (lane < 16) ? an0[0] : vn;
        if (lane < 32) {
            float r0 = sigm(bf2f(cxr) + gr);              // b_ir+b_hr pre-folded
            float z0 = sigm(bf2f(cxz) + gz);              // b_iz+b_hz pre-folded
            float n0 = tanh_f(bf2f(cxn) + r0 * (gn + bhnS));
            float hn = (1.f - z0) * n0 + z0 * hpS;
            hb[p ^ 1][mycol] = f2bf(hn);   // write the OTHER buffer: no read-WAR
            outputs[((size_t)b * Tt + t) * Hh + mycol] = hn;  // fire-and-forget
            hpS = hn;
        }
        p ^= 1;
        // LDS-only barrier: do NOT drain vmcnt (stores + prefetch stay in flight).
        asm volatile("s_waitcnt lgkmcnt(0)" ::: "memory");
        __builtin_amdgcn_s_barrier();
        asm volatile("" ::: "memory");
    }
    if (lane < 32) {
        hlast[b * Hh + mycol] = hpS;
    }
}

// ---------- launch ----------
extern "C" void kernel_launch(void* const* d_in, const int* in_sizes, int n_in,
                              void* d_out, int out_size, void* d_ws, size_t ws_size,
                              hipStream_t stream) {
    const float* inputs = (const float*)d_in[0];
    const float* hidden = (const float*)d_in[1];
    const float* W_w  = (const float*)d_in[2];
    const float* W_b  = (const float*)d_in[3];
    const float* V_w  = (const float*)d_in[4];
    const float* V_b  = (const float*)d_in[5];
    const float* w_ir = (const float*)d_in[6];
    const float* w_iz = (const float*)d_in[7];
    const float* w_in = (const float*)d_in[8];
    const float* b_ir = (const float*)d_in[9];
    const float* b_iz = (const float*)d_in[10];
    const float* b_in = (const float*)d_in[11];
    const float* w_hr = (const float*)d_in[12];
    const float* w_hz = (const float*)d_in[13];
    const float* w_hn = (const float*)d_in[14];
    const float* b_hr = (const float*)d_in[15];
    const float* b_hz = (const float*)d_in[16];
    const float* b_hn = (const float*)d_in[17];

    // workspace layout (~135.5 MB)
    float* hp = (float*)d_ws;                                  // 65536 f32
    float* partMS = hp + 65536;                                // 64*8*256*2 f32
    float* cbias = partMS + 262144;                            // 512 f32
    unsigned short* zbuf = (unsigned short*)(cbias + 512);     // 16.7M bf16
    unsigned short* ctx = zbuf;                                // alias: z dead after GEMM2
    unsigned short* xgb = zbuf + 16777216;                     // 3 x 16.7M bf16

    float* scores  = (float*)d_out;         // scores staged in outputs slot (dead before scan)
    float* outputs = (float*)d_out;
    float* hlast   = outputs + 16777216;
    float* x_attn  = hlast + 16384;

    hp_kernel<<<64, 256, 0, stream>>>(hidden, W_w, hp);
    bias_prep<<<1, 256, 0, stream>>>(b_ir, b_hr, b_iz, b_hz, cbias);

    gemm_k<0, false><<<dim3(512, 4), 512, 0, stream>>>(
        inputs, W_w, nullptr, nullptr, 512, 256,
        nullptr, nullptr, nullptr, hp, W_b, zbuf);

    gemm_k<1, true><<<dim3(512, 4), 512, 0, stream>>>(
        zbuf, V_w, nullptr, nullptr, 256, 0,
        V_b, nullptr, nullptr, nullptr, nullptr, scores);

    softmax_pass1<<<dim3(64, 8), 256, 0, stream>>>(scores, partMS);
    softmax_pass2<<<dim3(64, 8), 256, 0, stream>>>(scores, partMS, ctx, x_attn);

    gemm_k<2, true><<<dim3(512, 12), 512, 0, stream>>>(
        ctx, w_ir, w_iz, w_in, 256, 0,
        cbias, cbias + 256, b_in, nullptr, nullptr, xgb);

    scan_gru<<<64, 512, 0, stream>>>(
        xgb, w_hr, w_hz, w_hn, b_hn, hidden, outputs, hlast);
}

// Round 11
// 1453.988 us; speedup vs baseline: 1.0545x; 1.0545x over previous
//
#include <hip/hip_runtime.h>

#define DEVI __device__ __forceinline__

typedef float  f32x4  __attribute__((ext_vector_type(4)));
typedef __bf16 bf16x8 __attribute__((ext_vector_type(8)));
typedef unsigned short u16x8 __attribute__((ext_vector_type(8)));

// ---------- helpers ----------
DEVI unsigned short f2bf(float f) {
    unsigned u = __builtin_bit_cast(unsigned, f);
    unsigned r = (u + 0x7fffu + ((u >> 16) & 1u)) >> 16;
    return (unsigned short)r;
}
DEVI float bf2f(unsigned short s) {
    return __builtin_bit_cast(float, (unsigned)s << 16);
}
DEVI u16x8 pack8(float4 a, float4 b) {
    u16x8 p;
    p[0] = f2bf(a.x); p[1] = f2bf(a.y); p[2] = f2bf(a.z); p[3] = f2bf(a.w);
    p[4] = f2bf(b.x); p[5] = f2bf(b.y); p[6] = f2bf(b.z); p[7] = f2bf(b.w);
    return p;
}
DEVI f32x4 mfma16(u16x8 a, u16x8 b, f32x4 c) {
    return __builtin_amdgcn_mfma_f32_16x16x32_bf16(
        __builtin_bit_cast(bf16x8, a), __builtin_bit_cast(bf16x8, b), c, 0, 0, 0);
}
DEVI float sigm(float x)   { return 1.f / (1.f + __expf(-x)); }
DEVI float tanh_f(float x) { return 1.f - 2.f / (1.f + __expf(2.f * x)); }

// dims
#define Hh 256
#define Bb 64
#define Tt 1024
#define MROWS (Bb * Tt)   // 65536

// ---------- K0: hp[b][k] = sum_h hidden[b][h] * W_w[k][h] (first H cols) ----------
__global__ __launch_bounds__(256) void hp_kernel(const float* __restrict__ hid,
                                                 const float* __restrict__ Ww,
                                                 float* __restrict__ hp) {
    int b = blockIdx.x, k = threadIdx.x;
    __shared__ __align__(16) float hs[Hh];
    hs[k] = hid[b * Hh + k];
    __syncthreads();
    const float4* w4 = (const float4*)(Ww + (size_t)k * 512);
    const float4* h4 = (const float4*)hs;
    float acc = 0.f;
#pragma unroll 8
    for (int i = 0; i < 64; i++) {
        float4 a = w4[i], x = h4[i];
        acc += a.x * x.x + a.y * x.y + a.z * x.z + a.w * x.w;
    }
    hp[b * Hh + k] = acc;
}

// ---------- bias prep: cb[0][k]=b_ir+b_hr, cb[1][k]=b_iz+b_hz ----------
__global__ __launch_bounds__(256) void bias_prep(const float* __restrict__ b_ir,
                                                 const float* __restrict__ b_hr,
                                                 const float* __restrict__ b_iz,
                                                 const float* __restrict__ b_hz,
                                                 float* __restrict__ cb) {
    int k = threadIdx.x;
    cb[k] = b_ir[k] + b_hr[k];
    cb[256 + k] = b_iz[k] + b_hz[k];
}

// ---------- GEMM: OUT = epilogue( A(65536x256) @ W^T )  BM=128 BN=64 K=256 ----------
// EPI 0: z = tanh(acc + hp[b][c] + W_b[c]) -> bf16 [r][c]
// EPI 1: scores = acc + V_b[c] -> f32 [r][c]  + FUSED softmax partials:
//        block tile = one (b, tc) x 64-col chunk; per-col online (max,sumexp)
//        over the 128 rows -> partMS (same layout softmax_pass2 reads).
// EPI 2: xproj = acc + b_i[c] -> bf16 [mat][r][c]  (r = b*1024+t, coalesced)
template <int EPI, bool ABF16>
__global__ __launch_bounds__(512) void gemm_k(
    const void* __restrict__ Aab,
    const float* __restrict__ W0, const float* __restrict__ W1, const float* __restrict__ W2,
    int wstride, int wcoloff,
    const float* __restrict__ bv0, const float* __restrict__ bv1, const float* __restrict__ bv2,
    const float* __restrict__ hp, const float* __restrict__ Wb,
    float* __restrict__ pms,
    void* __restrict__ outv) {
    __shared__ __align__(16) unsigned short As[128 * 256];
    __shared__ __align__(16) unsigned short Bs[64 * 256];
    __shared__ float sredm[8][2][16], sredS[8][2][16];  // 2KB softmax partial scratch

    int tid = threadIdx.x;
    int bx = blockIdx.x, by = blockIdx.y;
    int mat = (EPI == 2) ? (by >> 2) : 0;
    int cb  = (EPI == 2) ? (by & 3) : by;
    int rowBase = bx * 128, colBase = cb * 64;
    const float* W  = (mat == 0) ? W0 : ((mat == 1) ? W1 : W2);
    const float* bv = (mat == 0) ? bv0 : ((mat == 1) ? bv1 : bv2);

    // stage A: 128 rows x 32 chunks(16B), swizzled g ^= (r&7)
    if (ABF16) {
        const unsigned short* A = (const unsigned short*)Aab;
#pragma unroll
        for (int i = 0; i < 8; i++) {
            int idx = i * 512 + tid, r = idx >> 5, g = idx & 31, gs = g ^ (r & 7);
            *(uint4*)&As[r * 256 + gs * 8] =
                *(const uint4*)(A + (((size_t)(rowBase + r)) << 8) + g * 8);
        }
    } else {
        const float* A = (const float*)Aab;
#pragma unroll
        for (int i = 0; i < 8; i++) {
            int idx = i * 512 + tid, r = idx >> 5, g = idx & 31, gs = g ^ (r & 7);
            const float* s = A + (((size_t)(rowBase + r)) << 8) + g * 8;
            float4 f0 = *(const float4*)s, f1 = *(const float4*)(s + 4);
            *(u16x8*)&As[r * 256 + gs * 8] = pack8(f0, f1);
        }
    }
    // stage B: 64 W-rows (output cols) x 32 chunks
#pragma unroll
    for (int i = 0; i < 4; i++) {
        int idx = i * 512 + tid, r = idx >> 5, g = idx & 31, gs = g ^ (r & 7);
        const float* s = W + (size_t)(colBase + r) * wstride + wcoloff + g * 8;
        float4 f0 = *(const float4*)s, f1 = *(const float4*)(s + 4);
        *(u16x8*)&Bs[r * 256 + gs * 8] = pack8(f0, f1);
    }
    __syncthreads();

    int wid = tid >> 6, lane = tid & 63, l15 = lane & 15, grp = lane >> 4;
    int wr = (wid >> 1) * 32, wc = (wid & 1) * 32;
    f32x4 acc[2][2] = {};
#pragma unroll
    for (int kc = 0; kc < 8; kc++) {
        u16x8 a[2], bb[2];
#pragma unroll
        for (int rt = 0; rt < 2; rt++) {
            int r = wr + rt * 16 + l15;
            int gs = (kc * 4 + grp) ^ (r & 7);
            a[rt] = *(const u16x8*)&As[r * 256 + gs * 8];
        }
#pragma unroll
        for (int ct = 0; ct < 2; ct++) {
            int r = wc + ct * 16 + l15;
            int gs = (kc * 4 + grp) ^ (r & 7);
            bb[ct] = *(const u16x8*)&Bs[r * 256 + gs * 8];
        }
#pragma unroll
        for (int rt = 0; rt < 2; rt++)
#pragma unroll
            for (int ct = 0; ct < 2; ct++)
                acc[rt][ct] = mfma16(a[rt], bb[ct], acc[rt][ct]);
    }
    // epilogue: D row = (lane>>4)*4 + i, col = lane&15
    float vv[2][2][4];
#pragma unroll
    for (int rt = 0; rt < 2; rt++)
#pragma unroll
        for (int ct = 0; ct < 2; ct++)
#pragma unroll
            for (int i = 0; i < 4; i++) {
                int rl = wr + rt * 16 + grp * 4 + i;
                int cl = wc + ct * 16 + l15;
                size_t r = (size_t)rowBase + rl;
                int c = colBase + cl;
                float v = acc[rt][ct][i];
                if (EPI == 0) {
                    v = tanh_f(v + hp[(r >> 10) * 256 + c] + Wb[c]);
                    ((unsigned short*)outv)[r * 256 + c] = f2bf(v);
                } else if (EPI == 1) {
                    float sc = v + bv[c];
                    vv[rt][ct][i] = sc;
                    ((float*)outv)[r * 256 + c] = sc;
                } else {
                    ((unsigned short*)outv)[(size_t)mat * 16777216 + r * 256 + c] =
                        f2bf(v + bv[c]);
                }
            }
    if constexpr (EPI == 1) {
        // fused softmax pass1: per-col (max, sumexp) over this block's 128 rows
        int b_ = rowBase >> 10, tc_ = (rowBase >> 7) & 7;
#pragma unroll
        for (int ct = 0; ct < 2; ct++) {
            float m = vv[0][ct][0];
#pragma unroll
            for (int rt = 0; rt < 2; rt++)
#pragma unroll
                for (int i = 0; i < 4; i++) m = fmaxf(m, vv[rt][ct][i]);
            float S = 0.f;
#pragma unroll
            for (int rt = 0; rt < 2; rt++)
#pragma unroll
                for (int i = 0; i < 4; i++) S += __expf(vv[rt][ct][i] - m);
            // butterfly across the 4 lane-groups (rows of this wave)
#pragma unroll
            for (int o = 16; o <= 32; o <<= 1) {
                float om = __shfl_xor(m, o, 64);
                float oS = __shfl_xor(S, o, 64);
                float nm = fmaxf(m, om);
                S = S * __expf(m - nm) + oS * __expf(om - nm);
                m = nm;
            }
            if (grp == 0) {  // lanes 0-15 hold the 32-row combined result
                sredm[wid][ct][l15] = m;
                sredS[wid][ct][l15] = S;
            }
        }
        __syncthreads();
        if (tid < 64) {  // combine the 4 row-wave-groups per column
            int cl = tid;
            int wcol = cl >> 5, ct = (cl >> 4) & 1, k15 = cl & 15;
            float m = -1e30f, S = 0.f;
#pragma unroll
            for (int rg = 0; rg < 4; rg++) {
                float om = sredm[rg * 2 + wcol][ct][k15];
                float oS = sredS[rg * 2 + wcol][ct][k15];
                float nm = fmaxf(m, om);
                S = S * __expf(m - nm) + oS * __expf(om - nm);
                m = nm;
            }
            int idx = (b_ * 8 + tc_) * Hh + colBase + cl;
            pms[idx * 2] = m;
            pms[idx * 2 + 1] = S;
        }
    }
}

// ---------- softmax pass 2: combine partials, emit ctx (bf16) and x_attn ----------
__global__ __launch_bounds__(256) void softmax_pass2(const float* __restrict__ scores,
                                                     const float* __restrict__ partMS,
                                                     unsigned short* __restrict__ ctx,
                                                     float* __restrict__ x_attn) {
    int b = blockIdx.x, tc = blockIdx.y;
    int tid = threadIdx.x, w = tid >> 6, lane = tid & 63;
    float mj[4], Sj[4];
#pragma unroll
    for (int j = 0; j < 4; j++) {
        int k = lane + j * 64;
        float m = -1e30f;
#pragma unroll
        for (int c = 0; c < 8; c++)
            m = fmaxf(m, partMS[((b * 8 + c) * Hh + k) * 2]);
        float S = 0.f;
#pragma unroll
        for (int c = 0; c < 8; c++) {
            int idx = (b * 8 + c) * Hh + k;
            S += partMS[idx * 2 + 1] * __expf(partMS[idx * 2] - m);
        }
        mj[j] = m;
        Sj[j] = 1.f / S;
    }
    for (int i = 0; i < 32; i++) {
        int t = tc * 128 + w * 32 + i;
        const float* sp = scores + ((size_t)b * Tt + t) * Hh;
        unsigned short* cp = ctx + ((size_t)b * Tt + t) * Hh;
        float accsm = 0.f;
#pragma unroll
        for (int j = 0; j < 4; j++) {
            int k = lane + j * 64;
            float s = sp[k];
            float sm = __expf(s - mj[j]) * Sj[j];
            accsm += sm;
            cp[k] = f2bf(s * sm);
        }
#pragma unroll
        for (int o = 32; o >= 1; o >>= 1) accsm += __shfl_xor(accsm, o, 64);
        if (lane == 0) x_attn[b * Tt + t] = accsm;
    }
}

// ---------- GRU scan (R9 configuration -- proven best: 1250us) ----------
// R10 post-mortem: all-AGPR (incl. w_hn) REGRESSED 1250->1310us -- the wn_lds
// stream was already hidden under the MFMA pipe; bigger AGPR footprint cost
// more than it saved. Reverted to R9: wfr/wfz in AGPR (128 regs, empty-asm
// coax), w_hn in LDS fragment-major (zero bank conflicts, imm-offset reads).
// Only change vs R9: xgb layout is now [mat][b*1024+t][c] (coalesced GEMM3
// writes); per-step scan read is still one contiguous 64B line per matrix.
__global__ __attribute__((amdgpu_flat_work_group_size(512, 512),
                          amdgpu_waves_per_eu(2, 2)))
void scan_gru(
    const unsigned short* __restrict__ xg,
    const float* __restrict__ whr, const float* __restrict__ whz, const float* __restrict__ whn,
    const float* __restrict__ bhn,
    const float* __restrict__ hidden,
    float* __restrict__ outputs, float* __restrict__ hlast) {
    __shared__ __align__(16) unsigned short wn_lds[65536];  // w_hn, fragment-major (128KB)
    __shared__ __align__(16) unsigned short hb[2][Hh];      // h double-buffer (bf16)
    int b = blockIdx.x;
    int tid = threadIdx.x, w = tid >> 6, lane = tid & 63;
    int grp = lane >> 4;

    // stage w_hn -> LDS fragment-major: frag=(col>>4)*8+kc holds 64 lanes x 16B;
    // lane slot (grp*16+l15) <- whn[col=tile*16+l15][kc*32+grp*8 ..+8].
    for (int it = 0; it < 16; ++it) {
        int q = it * 512 + tid;
        int frag = q >> 6, lslot = q & 63;
        int col = ((frag >> 3) << 4) | (lslot & 15);
        int koff = (frag & 7) * 32 + (lslot >> 4) * 8;
        const float* s = whn + (size_t)col * Hh + koff;
        *(u16x8*)&wn_lds[frag * 512 + lslot * 8] = pack8(*(const float4*)s, *(const float4*)(s + 4));
    }

    // w_hr / w_hz fragments: wave owns cols [32w, 32w+32), 2 col-tiles x 8 K-chunks
    u16x8 wfr[2][8], wfz[2][8];
#pragma unroll
    for (int ct = 0; ct < 2; ct++) {
        int col = w * 32 + ct * 16 + (lane & 15);
#pragma unroll
        for (int kc = 0; kc < 8; kc++) {
            const float* s1 = whr + (size_t)col * Hh + kc * 32 + grp * 8;
            wfr[ct][kc] = pack8(*(const float4*)s1, *(const float4*)(s1 + 4));
            const float* s2 = whz + (size_t)col * Hh + kc * 32 + grp * 8;
            wfz[ct][kc] = pack8(*(const float4*)s2, *(const float4*)(s2 + 4));
        }
    }
    // Coax the 32 fragments (128 regs) into the AGPR half of the unified RF
    // (value-preserving empty asm; R8/R9 verified: kills the spill).
    asm volatile("" : "+a"(wfr[0][0]), "+a"(wfr[0][1]), "+a"(wfr[0][2]), "+a"(wfr[0][3]),
                      "+a"(wfr[0][4]), "+a"(wfr[0][5]), "+a"(wfr[0][6]), "+a"(wfr[0][7]));
    asm volatile("" : "+a"(wfr[1][0]), "+a"(wfr[1][1]), "+a"(wfr[1][2]), "+a"(wfr[1][3]),
                      "+a"(wfr[1][4]), "+a"(wfr[1][5]), "+a"(wfr[1][6]), "+a"(wfr[1][7]));
    asm volatile("" : "+a"(wfz[0][0]), "+a"(wfz[0][1]), "+a"(wfz[0][2]), "+a"(wfz[0][3]),
                      "+a"(wfz[0][4]), "+a"(wfz[0][5]), "+a"(wfz[0][6]), "+a"(wfz[0][7]));
    asm volatile("" : "+a"(wfz[1][0]), "+a"(wfz[1][1]), "+a"(wfz[1][2]), "+a"(wfz[1][3]),
                      "+a"(wfz[1][4]), "+a"(wfz[1][5]), "+a"(wfz[1][6]), "+a"(wfz[1][7]));

    // per-lane state: lanes 0-15 own col0 block, lanes 16-31 own col1 block
    int mycol = w * 32 + (lane & 31);
    int wnb = (w * 16) * 512 + lane * 8;  // fragment-major base (elems); +8*512 for ct=1
    float bhnS = 0.f, hpS = 0.f;
    if (lane < 32) {
        bhnS = bhn[mycol];
        hpS = hidden[b * Hh + mycol];
        hb[0][mycol] = f2bf(hpS);
        outputs[((size_t)b * Tt) * Hh + mycol] = hpS;  // outputs[:,0,:] = h0 exact
    }
    const unsigned short* xr = xg;
    const unsigned short* xz = xg + 16777216;
    const unsigned short* xn = xg + 33554432;
    unsigned short pxr = 0, pxz = 0, pxn = 0;
    if (lane < 32) {
        size_t off = ((size_t)b * Tt + 1) * Hh + mycol;  // t=1
        pxr = xr[off]; pxz = xz[off]; pxn = xn[off];
    }
    __syncthreads();

    int p = 0;
    for (int t = 1; t < Tt; t++) {
        unsigned short cxr = pxr, cxz = pxz, cxn = pxn;
        int tnext = (t + 1 < Tt) ? t + 1 : t;
        if (lane < 32) {  // prefetch next step (latency hidden under MFMAs)
            size_t off = ((size_t)b * Tt + tnext) * Hh + mycol;
            pxr = xr[off]; pxz = xz[off]; pxn = xn[off];
        }
        f32x4 ar0 = {0.f, 0.f, 0.f, 0.f}, ar1 = {0.f, 0.f, 0.f, 0.f};
        f32x4 az0 = {0.f, 0.f, 0.f, 0.f}, az1 = {0.f, 0.f, 0.f, 0.f};
        f32x4 an0 = {0.f, 0.f, 0.f, 0.f}, an1 = {0.f, 0.f, 0.f, 0.f};
#pragma unroll
        for (int kc = 0; kc < 8; kc++) {
            u16x8 af = *(const u16x8*)&hb[p][kc * 32 + grp * 8];  // broadcast read
            ar0 = mfma16(af, wfr[0][kc], ar0);
            ar1 = mfma16(af, wfr[1][kc], ar1);
            az0 = mfma16(af, wfz[0][kc], az0);
            az1 = mfma16(af, wfz[1][kc], az1);
            u16x8 wn0 = *(const u16x8*)&wn_lds[wnb + kc * 512];           // linear sweep
            u16x8 wn1 = *(const u16x8*)&wn_lds[wnb + 8 * 512 + kc * 512]; // imm offsets
            an0 = mfma16(af, wn0, an0);
            an1 = mfma16(af, wn1, an1);
        }
        // move col1-block accs (row 0 lives in lanes 0-15) to lanes 16-31
        float vr = __shfl(ar1[0], lane & 15);
        float vz = __shfl(az1[0], lane & 15);
        float vn = __shfl(an1[0], lane & 15);
        float gr = (lane < 16) ? ar0[0] : vr;
        float gz = (lane < 16) ? az0[0] : vz;
        float gn = (lane < 16) ? an0[0] : vn;
        if (lane < 32) {
            float r0 = sigm(bf2f(cxr) + gr);              // b_ir+b_hr pre-folded
            float z0 = sigm(bf2f(cxz) + gz);              // b_iz+b_hz pre-folded
            float n0 = tanh_f(bf2f(cxn) + r0 * (gn + bhnS));
            float hn = (1.f - z0) * n0 + z0 * hpS;
            hb[p ^ 1][mycol] = f2bf(hn);   // write the OTHER buffer: no read-WAR
            outputs[((size_t)b * Tt + t) * Hh + mycol] = hn;  // fire-and-forget
            hpS = hn;
        }
        p ^= 1;
        // LDS-only barrier: do NOT drain vmcnt (stores + prefetch stay in flight).
        asm volatile("s_waitcnt lgkmcnt(0)" ::: "memory");
        __builtin_amdgcn_s_barrier();
        asm volatile("" ::: "memory");
    }
    if (lane < 32) {
        hlast[b * Hh + mycol] = hpS;
    }
}

// ---------- launch ----------
extern "C" void kernel_launch(void* const* d_in, const int* in_sizes, int n_in,
                              void* d_out, int out_size, void* d_ws, size_t ws_size,
                              hipStream_t stream) {
    const float* inputs = (const float*)d_in[0];
    const float* hidden = (const float*)d_in[1];
    const float* W_w  = (const float*)d_in[2];
    const float* W_b  = (const float*)d_in[3];
    const float* V_w  = (const float*)d_in[4];
    const float* V_b  = (const float*)d_in[5];
    const float* w_ir = (const float*)d_in[6];
    const float* w_iz = (const float*)d_in[7];
    const float* w_in = (const float*)d_in[8];
    const float* b_ir = (const float*)d_in[9];
    const float* b_iz = (const float*)d_in[10];
    const float* b_in = (const float*)d_in[11];
    const float* w_hr = (const float*)d_in[12];
    const float* w_hz = (const float*)d_in[13];
    const float* w_hn = (const float*)d_in[14];
    const float* b_hr = (const float*)d_in[15];
    const float* b_hz = (const float*)d_in[16];
    const float* b_hn = (const float*)d_in[17];

    // workspace layout (~129.3 MB)
    float* hp = (float*)d_ws;                                  // 65536 f32
    float* partMS = hp + 65536;                                // 64*8*256*2 f32
    float* cbias = partMS + 262144;                            // 512 f32
    unsigned short* zbuf = (unsigned short*)(cbias + 512);     // 16.7M bf16
    unsigned short* ctx = zbuf;                                // alias: z dead after GEMM2
    unsigned short* xgb = zbuf + 16777216;                     // 3 x 16.7M bf16

    float* scores  = (float*)d_out;         // scores staged in outputs slot (dead before scan)
    float* outputs = (float*)d_out;
    float* hlast   = outputs + 16777216;
    float* x_attn  = hlast + 16384;

    hp_kernel<<<64, 256, 0, stream>>>(hidden, W_w, hp);
    bias_prep<<<1, 256, 0, stream>>>(b_ir, b_hr, b_iz, b_hz, cbias);

    gemm_k<0, false><<<dim3(512, 4), 512, 0, stream>>>(
        inputs, W_w, nullptr, nullptr, 512, 256,
        nullptr, nullptr, nullptr, hp, W_b, nullptr, zbuf);

    // GEMM2 with fused softmax pass1 (writes scores + partMS)
    gemm_k<1, true><<<dim3(512, 4), 512, 0, stream>>>(
        zbuf, V_w, nullptr, nullptr, 256, 0,
        V_b, nullptr, nullptr, nullptr, nullptr, partMS, scores);

    softmax_pass2<<<dim3(64, 8), 256, 0, stream>>>(scores, partMS, ctx, x_attn);

    gemm_k<2, true><<<dim3(512, 12), 512, 0, stream>>>(
        ctx, w_ir, w_iz, w_in, 256, 0,
        cbias, cbias + 256, b_in, nullptr, nullptr, nullptr, xgb);

    scan_gru<<<64, 512, 0, stream>>>(
        xgb, w_hr, w_hz, w_hn, b_hn, hidden, outputs, hlast);
}

// Round 12
// 1368.475 us; speedup vs baseline: 1.1204x; 1.0625x over previous
//
#include <hip/hip_runtime.h>

#define DEVI __device__ __forceinline__

typedef float  f32x4  __attribute__((ext_vector_type(4)));
typedef __bf16 bf16x8 __attribute__((ext_vector_type(8)));
typedef unsigned short u16x8 __attribute__((ext_vector_type(8)));

// ---------- helpers ----------
DEVI unsigned short f2bf(float f) {
    unsigned u = __builtin_bit_cast(unsigned, f);
    unsigned r = (u + 0x7fffu + ((u >> 16) & 1u)) >> 16;
    return (unsigned short)r;
}
DEVI float bf2f(unsigned short s) {
    return __builtin_bit_cast(float, (unsigned)s << 16);
}
DEVI u16x8 pack8(float4 a, float4 b) {
    u16x8 p;
    p[0] = f2bf(a.x); p[1] = f2bf(a.y); p[2] = f2bf(a.z); p[3] = f2bf(a.w);
    p[4] = f2bf(b.x); p[5] = f2bf(b.y); p[6] = f2bf(b.z); p[7] = f2bf(b.w);
    return p;
}
DEVI f32x4 mfma16(u16x8 a, u16x8 b, f32x4 c) {
    return __builtin_amdgcn_mfma_f32_16x16x32_bf16(
        __builtin_bit_cast(bf16x8, a), __builtin_bit_cast(bf16x8, b), c, 0, 0, 0);
}
DEVI float sigm(float x)   { return 1.f / (1.f + __expf(-x)); }
DEVI float tanh_f(float x) { return 1.f - 2.f / (1.f + __expf(2.f * x)); }

// dims
#define Hh 256
#define Bb 64
#define Tt 1024

// ---------- K0: hp[b][k] = sum_h hidden[b][h] * W_w[k][h] (first H cols) ----------
__global__ __launch_bounds__(256) void hp_kernel(const float* __restrict__ hid,
                                                 const float* __restrict__ Ww,
                                                 float* __restrict__ hp) {
    int b = blockIdx.x, k = threadIdx.x;
    __shared__ __align__(16) float hs[Hh];
    hs[k] = hid[b * Hh + k];
    __syncthreads();
    const float4* w4 = (const float4*)(Ww + (size_t)k * 512);
    const float4* h4 = (const float4*)hs;
    float acc = 0.f;
#pragma unroll 8
    for (int i = 0; i < 64; i++) {
        float4 a = w4[i], x = h4[i];
        acc += a.x * x.x + a.y * x.y + a.z * x.z + a.w * x.w;
    }
    hp[b * Hh + k] = acc;
}

// ---------- bias prep: cb[0][k]=b_ir+b_hr, cb[1][k]=b_iz+b_hz ----------
__global__ __launch_bounds__(256) void bias_prep(const float* __restrict__ b_ir,
                                                 const float* __restrict__ b_hr,
                                                 const float* __restrict__ b_iz,
                                                 const float* __restrict__ b_hz,
                                                 float* __restrict__ cb) {
    int k = threadIdx.x;
    cb[k] = b_ir[k] + b_hr[k];
    cb[256 + k] = b_iz[k] + b_hz[k];
}

// ---------- GEMM 128x128 tile (EPI0 / EPI2): 8 waves in 2x4, 512 MFMA/block ----------
// EPI 0: z = tanh(acc + hp[b][c] + W_b[c]) -> bf16 [r][c]
// EPI 2: xproj = acc + b_i[c] -> bf16 [mat][r][c]  (r = b*1024+t)
template <int EPI, bool ABF16>
__global__ __launch_bounds__(512) void gemm128(
    const void* __restrict__ Aab,
    const float* __restrict__ W0, const float* __restrict__ W1, const float* __restrict__ W2,
    int wstride, int wcoloff,
    const float* __restrict__ bv0, const float* __restrict__ bv1, const float* __restrict__ bv2,
    const float* __restrict__ hp, const float* __restrict__ Wb,
    void* __restrict__ outv) {
    __shared__ __align__(16) unsigned short As[128 * 256];  // 64KB
    __shared__ __align__(16) unsigned short Bs[128 * 256];  // 64KB (128KB total: 1 WG/CU)

    int tid = threadIdx.x;
    int bx = blockIdx.x, by = blockIdx.y;
    int mat = (EPI == 2) ? (by >> 1) : 0;
    int cb  = (EPI == 2) ? (by & 1) : by;
    int rowBase = bx * 128, colBase = cb * 128;
    const float* W  = (mat == 0) ? W0 : ((mat == 1) ? W1 : W2);
    const float* bv = (mat == 0) ? bv0 : ((mat == 1) ? bv1 : bv2);

    // stage A: 128 rows x 32 chunks(16B), swizzled g ^= (r&7)
    if (ABF16) {
        const unsigned short* A = (const unsigned short*)Aab;
#pragma unroll
        for (int i = 0; i < 8; i++) {
            int idx = i * 512 + tid, r = idx >> 5, g = idx & 31, gs = g ^ (r & 7);
            *(uint4*)&As[r * 256 + gs * 8] =
                *(const uint4*)(A + (((size_t)(rowBase + r)) << 8) + g * 8);
        }
    } else {
        const float* A = (const float*)Aab;
#pragma unroll
        for (int i = 0; i < 8; i++) {
            int idx = i * 512 + tid, r = idx >> 5, g = idx & 31, gs = g ^ (r & 7);
            const float* s = A + (((size_t)(rowBase + r)) << 8) + g * 8;
            float4 f0 = *(const float4*)s, f1 = *(const float4*)(s + 4);
            *(u16x8*)&As[r * 256 + gs * 8] = pack8(f0, f1);
        }
    }
    // stage B: 128 W-rows (output cols) x 32 chunks
#pragma unroll
    for (int i = 0; i < 8; i++) {
        int idx = i * 512 + tid, r = idx >> 5, g = idx & 31, gs = g ^ (r & 7);
        const float* s = W + (size_t)(colBase + r) * wstride + wcoloff + g * 8;
        float4 f0 = *(const float4*)s, f1 = *(const float4*)(s + 4);
        *(u16x8*)&Bs[r * 256 + gs * 8] = pack8(f0, f1);
    }
    __syncthreads();

    int wid = tid >> 6, lane = tid & 63, l15 = lane & 15, grp = lane >> 4;
    int wr = (wid >> 2) * 64, wc = (wid & 3) * 32;   // wave tile: 64 rows x 32 cols
    f32x4 acc[4][2] = {};
#pragma unroll
    for (int kc = 0; kc < 8; kc++) {
        u16x8 a[4], bb[2];
#pragma unroll
        for (int rt = 0; rt < 4; rt++) {
            int r = wr + rt * 16 + l15;
            int gs = (kc * 4 + grp) ^ (r & 7);
            a[rt] = *(const u16x8*)&As[r * 256 + gs * 8];
        }
#pragma unroll
        for (int ct = 0; ct < 2; ct++) {
            int r = wc + ct * 16 + l15;
            int gs = (kc * 4 + grp) ^ (r & 7);
            bb[ct] = *(const u16x8*)&Bs[r * 256 + gs * 8];
        }
#pragma unroll
        for (int rt = 0; rt < 4; rt++)
#pragma unroll
            for (int ct = 0; ct < 2; ct++)
                acc[rt][ct] = mfma16(a[rt], bb[ct], acc[rt][ct]);
    }
    // epilogue: D row = (lane>>4)*4 + i, col = lane&15
#pragma unroll
    for (int rt = 0; rt < 4; rt++)
#pragma unroll
        for (int ct = 0; ct < 2; ct++)
#pragma unroll
            for (int i = 0; i < 4; i++) {
                int rl = wr + rt * 16 + grp * 4 + i;
                int cl = wc + ct * 16 + l15;
                size_t r = (size_t)rowBase + rl;
                int c = colBase + cl;
                float v = acc[rt][ct][i];
                if (EPI == 0) {
                    v = tanh_f(v + hp[(r >> 10) * 256 + c] + Wb[c]);
                    ((unsigned short*)outv)[r * 256 + c] = f2bf(v);
                } else {
                    ((unsigned short*)outv)[(size_t)mat * 16777216 + r * 256 + c] =
                        f2bf(v + bv[c]);
                }
            }
}

// ---------- GEMM 128x64 (EPI1 only): scores + fused softmax pass1 ----------
__global__ __launch_bounds__(512) void gemm_k1(
    const void* __restrict__ Aab,
    const float* __restrict__ W0, int wstride, int wcoloff,
    const float* __restrict__ bv0,
    float* __restrict__ pms,
    void* __restrict__ outv) {
    __shared__ __align__(16) unsigned short As[128 * 256];
    __shared__ __align__(16) unsigned short Bs[64 * 256];
    __shared__ float sredm[8][2][16], sredS[8][2][16];

    int tid = threadIdx.x;
    int bx = blockIdx.x, by = blockIdx.y;
    int rowBase = bx * 128, colBase = by * 64;
    const float* W = W0;
    const float* bv = bv0;

    const unsigned short* A = (const unsigned short*)Aab;
#pragma unroll
    for (int i = 0; i < 8; i++) {
        int idx = i * 512 + tid, r = idx >> 5, g = idx & 31, gs = g ^ (r & 7);
        *(uint4*)&As[r * 256 + gs * 8] =
            *(const uint4*)(A + (((size_t)(rowBase + r)) << 8) + g * 8);
    }
#pragma unroll
    for (int i = 0; i < 4; i++) {
        int idx = i * 512 + tid, r = idx >> 5, g = idx & 31, gs = g ^ (r & 7);
        const float* s = W + (size_t)(colBase + r) * wstride + wcoloff + g * 8;
        float4 f0 = *(const float4*)s, f1 = *(const float4*)(s + 4);
        *(u16x8*)&Bs[r * 256 + gs * 8] = pack8(f0, f1);
    }
    __syncthreads();

    int wid = tid >> 6, lane = tid & 63, l15 = lane & 15, grp = lane >> 4;
    int wr = (wid >> 1) * 32, wc = (wid & 1) * 32;
    f32x4 acc[2][2] = {};
#pragma unroll
    for (int kc = 0; kc < 8; kc++) {
        u16x8 a[2], bb[2];
#pragma unroll
        for (int rt = 0; rt < 2; rt++) {
            int r = wr + rt * 16 + l15;
            int gs = (kc * 4 + grp) ^ (r & 7);
            a[rt] = *(const u16x8*)&As[r * 256 + gs * 8];
        }
#pragma unroll
        for (int ct = 0; ct < 2; ct++) {
            int r = wc + ct * 16 + l15;
            int gs = (kc * 4 + grp) ^ (r & 7);
            bb[ct] = *(const u16x8*)&Bs[r * 256 + gs * 8];
        }
#pragma unroll
        for (int rt = 0; rt < 2; rt++)
#pragma unroll
            for (int ct = 0; ct < 2; ct++)
                acc[rt][ct] = mfma16(a[rt], bb[ct], acc[rt][ct]);
    }
    float vv[2][2][4];
#pragma unroll
    for (int rt = 0; rt < 2; rt++)
#pragma unroll
        for (int ct = 0; ct < 2; ct++)
#pragma unroll
            for (int i = 0; i < 4; i++) {
                int rl = wr + rt * 16 + grp * 4 + i;
                int cl = wc + ct * 16 + l15;
                size_t r = (size_t)rowBase + rl;
                int c = colBase + cl;
                float sc = acc[rt][ct][i] + bv[c];
                vv[rt][ct][i] = sc;
                ((float*)outv)[r * 256 + c] = sc;
            }
    // fused softmax pass1: per-col (max, sumexp) over this block's 128 rows
    int b_ = rowBase >> 10, tc_ = (rowBase >> 7) & 7;
#pragma unroll
    for (int ct = 0; ct < 2; ct++) {
        float m = vv[0][ct][0];
#pragma unroll
        for (int rt = 0; rt < 2; rt++)
#pragma unroll
            for (int i = 0; i < 4; i++) m = fmaxf(m, vv[rt][ct][i]);
        float S = 0.f;
#pragma unroll
        for (int rt = 0; rt < 2; rt++)
#pragma unroll
            for (int i = 0; i < 4; i++) S += __expf(vv[rt][ct][i] - m);
#pragma unroll
        for (int o = 16; o <= 32; o <<= 1) {
            float om = __shfl_xor(m, o, 64);
            float oS = __shfl_xor(S, o, 64);
            float nm = fmaxf(m, om);
            S = S * __expf(m - nm) + oS * __expf(om - nm);
            m = nm;
        }
        if (grp == 0) {
            sredm[wid][ct][l15] = m;
            sredS[wid][ct][l15] = S;
        }
    }
    __syncthreads();
    if (tid < 64) {
        int cl = tid;
        int wcol = cl >> 5, ct = (cl >> 4) & 1, k15 = cl & 15;
        float m = -1e30f, S = 0.f;
#pragma unroll
        for (int rg = 0; rg < 4; rg++) {
            float om = sredm[rg * 2 + wcol][ct][k15];
            float oS = sredS[rg * 2 + wcol][ct][k15];
            float nm = fmaxf(m, om);
            S = S * __expf(m - nm) + oS * __expf(om - nm);
            m = nm;
        }
        int idx = (b_ * 8 + tc_) * Hh + colBase + cl;
        pms[idx * 2] = m;
        pms[idx * 2 + 1] = S;
    }
}

// ---------- softmax pass 2: combine partials, emit ctx (bf16) and x_attn ----------
__global__ __launch_bounds__(256) void softmax_pass2(const float* __restrict__ scores,
                                                     const float* __restrict__ partMS,
                                                     unsigned short* __restrict__ ctx,
                                                     float* __restrict__ x_attn) {
    int b = blockIdx.x, tc = blockIdx.y;
    int tid = threadIdx.x, w = tid >> 6, lane = tid & 63;
    float mj[4], Sj[4];
#pragma unroll
    for (int j = 0; j < 4; j++) {
        int k = lane + j * 64;
        float m = -1e30f;
#pragma unroll
        for (int c = 0; c < 8; c++)
            m = fmaxf(m, partMS[((b * 8 + c) * Hh + k) * 2]);
        float S = 0.f;
#pragma unroll
        for (int c = 0; c < 8; c++) {
            int idx = (b * 8 + c) * Hh + k;
            S += partMS[idx * 2 + 1] * __expf(partMS[idx * 2] - m);
        }
        mj[j] = m;
        Sj[j] = 1.f / S;
    }
    for (int i = 0; i < 32; i++) {
        int t = tc * 128 + w * 32 + i;
        const float* sp = scores + ((size_t)b * Tt + t) * Hh;
        unsigned short* cp = ctx + ((size_t)b * Tt + t) * Hh;
        float accsm = 0.f;
#pragma unroll
        for (int j = 0; j < 4; j++) {
            int k = lane + j * 64;
            float s = sp[k];
            float sm = __expf(s - mj[j]) * Sj[j];
            accsm += sm;
            cp[k] = f2bf(s * sm);
        }
#pragma unroll
        for (int o = 32; o >= 1; o >>= 1) accsm += __shfl_xor(accsm, o, 64);
        if (lane == 0) x_attn[b * Tt + t] = accsm;
    }
}

// ---------- GRU scan (R9 config; R12: shfl-free epilogue) ----------
// All 16 A-rows are IDENTICAL (af is a broadcast read: each lane's fragment
// depends only on grp) -> every D row is bitwise identical. Lanes 16-31
// (grp=1, reg 0 = row 4) already hold the same ar1[0]/az1[0]/an1[0] values
// as lanes 0-15 -> the R9 shfl redistribution was a no-op; read directly.
__global__ __attribute__((amdgpu_flat_work_group_size(512, 512),
                          amdgpu_waves_per_eu(2, 2)))
void scan_gru(
    const unsigned short* __restrict__ xg,
    const float* __restrict__ whr, const float* __restrict__ whz, const float* __restrict__ whn,
    const float* __restrict__ bhn,
    const float* __restrict__ hidden,
    float* __restrict__ outputs, float* __restrict__ hlast) {
    __shared__ __align__(16) unsigned short wn_lds[65536];  // w_hn, fragment-major (128KB)
    __shared__ __align__(16) unsigned short hb[2][Hh];      // h double-buffer (bf16)
    int b = blockIdx.x;
    int tid = threadIdx.x, w = tid >> 6, lane = tid & 63;
    int grp = lane >> 4;

    // stage w_hn -> LDS fragment-major (linear writes, conflict-free reads)
    for (int it = 0; it < 16; ++it) {
        int q = it * 512 + tid;
        int frag = q >> 6, lslot = q & 63;
        int col = ((frag >> 3) << 4) | (lslot & 15);
        int koff = (frag & 7) * 32 + (lslot >> 4) * 8;
        const float* s = whn + (size_t)col * Hh + koff;
        *(u16x8*)&wn_lds[frag * 512 + lslot * 8] = pack8(*(const float4*)s, *(const float4*)(s + 4));
    }

    // w_hr / w_hz fragments: wave owns cols [32w, 32w+32), 2 col-tiles x 8 K-chunks
    u16x8 wfr[2][8], wfz[2][8];
#pragma unroll
    for (int ct = 0; ct < 2; ct++) {
        int col = w * 32 + ct * 16 + (lane & 15);
#pragma unroll
        for (int kc = 0; kc < 8; kc++) {
            const float* s1 = whr + (size_t)col * Hh + kc * 32 + grp * 8;
            wfr[ct][kc] = pack8(*(const float4*)s1, *(const float4*)(s1 + 4));
            const float* s2 = whz + (size_t)col * Hh + kc * 32 + grp * 8;
            wfz[ct][kc] = pack8(*(const float4*)s2, *(const float4*)(s2 + 4));
        }
    }
    // Coax the 32 fragments (128 regs) into the AGPR half (R8/R9 verified).
    asm volatile("" : "+a"(wfr[0][0]), "+a"(wfr[0][1]), "+a"(wfr[0][2]), "+a"(wfr[0][3]),
                      "+a"(wfr[0][4]), "+a"(wfr[0][5]), "+a"(wfr[0][6]), "+a"(wfr[0][7]));
    asm volatile("" : "+a"(wfr[1][0]), "+a"(wfr[1][1]), "+a"(wfr[1][2]), "+a"(wfr[1][3]),
                      "+a"(wfr[1][4]), "+a"(wfr[1][5]), "+a"(wfr[1][6]), "+a"(wfr[1][7]));
    asm volatile("" : "+a"(wfz[0][0]), "+a"(wfz[0][1]), "+a"(wfz[0][2]), "+a"(wfz[0][3]),
                      "+a"(wfz[0][4]), "+a"(wfz[0][5]), "+a"(wfz[0][6]), "+a"(wfz[0][7]));
    asm volatile("" : "+a"(wfz[1][0]), "+a"(wfz[1][1]), "+a"(wfz[1][2]), "+a"(wfz[1][3]),
                      "+a"(wfz[1][4]), "+a"(wfz[1][5]), "+a"(wfz[1][6]), "+a"(wfz[1][7]));

    // per-lane state: lanes 0-15 own col-tile0, lanes 16-31 own col-tile1
    int mycol = w * 32 + (lane & 31);
    int wnb = (w * 16) * 512 + lane * 8;  // fragment-major base; +8*512 for ct=1
    float bhnS = 0.f, hpS = 0.f;
    if (lane < 32) {
        bhnS = bhn[mycol];
        hpS = hidden[b * Hh + mycol];
        hb[0][mycol] = f2bf(hpS);
        outputs[((size_t)b * Tt) * Hh + mycol] = hpS;  // outputs[:,0,:] = h0 exact
    }
    const unsigned short* xr = xg;
    const unsigned short* xz = xg + 16777216;
    const unsigned short* xn = xg + 33554432;
    unsigned short pxr = 0, pxz = 0, pxn = 0;
    if (lane < 32) {
        size_t off = ((size_t)b * Tt + 1) * Hh + mycol;  // t=1
        pxr = xr[off]; pxz = xz[off]; pxn = xn[off];
    }
    __syncthreads();

    int p = 0;
    for (int t = 1; t < Tt; t++) {
        unsigned short cxr = pxr, cxz = pxz, cxn = pxn;
        int tnext = (t + 1 < Tt) ? t + 1 : t;
        if (lane < 32) {  // prefetch next step (latency hidden under MFMAs)
            size_t off = ((size_t)b * Tt + tnext) * Hh + mycol;
            pxr = xr[off]; pxz = xz[off]; pxn = xn[off];
        }
        f32x4 ar0 = {0.f, 0.f, 0.f, 0.f}, ar1 = {0.f, 0.f, 0.f, 0.f};
        f32x4 az0 = {0.f, 0.f, 0.f, 0.f}, az1 = {0.f, 0.f, 0.f, 0.f};
        f32x4 an0 = {0.f, 0.f, 0.f, 0.f}, an1 = {0.f, 0.f, 0.f, 0.f};
#pragma unroll
        for (int kc = 0; kc < 8; kc++) {
            u16x8 af = *(const u16x8*)&hb[p][kc * 32 + grp * 8];  // broadcast read
            ar0 = mfma16(af, wfr[0][kc], ar0);
            ar1 = mfma16(af, wfr[1][kc], ar1);
            az0 = mfma16(af, wfz[0][kc], az0);
            az1 = mfma16(af, wfz[1][kc], az1);
            u16x8 wn0 = *(const u16x8*)&wn_lds[wnb + kc * 512];           // linear sweep
            u16x8 wn1 = *(const u16x8*)&wn_lds[wnb + 8 * 512 + kc * 512]; // imm offsets
            an0 = mfma16(af, wn0, an0);
            an1 = mfma16(af, wn1, an1);
        }
        // all D rows identical -> lanes 16-31's reg0 of *1 accs hold tile1 cols
        float gr = (lane < 16) ? ar0[0] : ar1[0];
        float gz = (lane < 16) ? az0[0] : az1[0];
        float gn = (lane < 16) ? an0[0] : an1[0];
        if (lane < 32) {
            float r0 = sigm(bf2f(cxr) + gr);              // b_ir+b_hr pre-folded
            float z0 = sigm(bf2f(cxz) + gz);              // b_iz+b_hz pre-folded
            float n0 = tanh_f(bf2f(cxn) + r0 * (gn + bhnS));
            float hn = (1.f - z0) * n0 + z0 * hpS;
            hb[p ^ 1][mycol] = f2bf(hn);   // write the OTHER buffer: no read-WAR
            outputs[((size_t)b * Tt + t) * Hh + mycol] = hn;  // fire-and-forget
            hpS = hn;
        }
        p ^= 1;
        // LDS-only barrier: do NOT drain vmcnt (stores + prefetch stay in flight).
        asm volatile("s_waitcnt lgkmcnt(0)" ::: "memory");
        __builtin_amdgcn_s_barrier();
        asm volatile("" ::: "memory");
    }
    if (lane < 32) {
        hlast[b * Hh + mycol] = hpS;
    }
}

// ---------- launch ----------
extern "C" void kernel_launch(void* const* d_in, const int* in_sizes, int n_in,
                              void* d_out, int out_size, void* d_ws, size_t ws_size,
                              hipStream_t stream) {
    const float* inputs = (const float*)d_in[0];
    const float* hidden = (const float*)d_in[1];
    const float* W_w  = (const float*)d_in[2];
    const float* W_b  = (const float*)d_in[3];
    const float* V_w  = (const float*)d_in[4];
    const float* V_b  = (const float*)d_in[5];
    const float* w_ir = (const float*)d_in[6];
    const float* w_iz = (const float*)d_in[7];
    const float* w_in = (const float*)d_in[8];
    const float* b_ir = (const float*)d_in[9];
    const float* b_iz = (const float*)d_in[10];
    const float* b_in = (const float*)d_in[11];
    const float* w_hr = (const float*)d_in[12];
    const float* w_hz = (const float*)d_in[13];
    const float* w_hn = (const float*)d_in[14];
    const float* b_hr = (const float*)d_in[15];
    const float* b_hz = (const float*)d_in[16];
    const float* b_hn = (const float*)d_in[17];

    // workspace layout (~129.3 MB)
    float* hp = (float*)d_ws;                                  // 65536 f32
    float* partMS = hp + 65536;                                // 64*8*256*2 f32
    float* cbias = partMS + 262144;                            // 512 f32
    unsigned short* zbuf = (unsigned short*)(cbias + 512);     // 16.7M bf16
    unsigned short* ctx = zbuf;                                // alias: z dead after GEMM2
    unsigned short* xgb = zbuf + 16777216;                     // 3 x 16.7M bf16

    float* scores  = (float*)d_out;         // scores staged in outputs slot (dead before scan)
    float* outputs = (float*)d_out;
    float* hlast   = outputs + 16777216;
    float* x_attn  = hlast + 16384;

    hp_kernel<<<64, 256, 0, stream>>>(hidden, W_w, hp);
    bias_prep<<<1, 256, 0, stream>>>(b_ir, b_hr, b_iz, b_hz, cbias);

    gemm128<0, false><<<dim3(512, 2), 512, 0, stream>>>(
        inputs, W_w, nullptr, nullptr, 512, 256,
        nullptr, nullptr, nullptr, hp, W_b, zbuf);

    // GEMM2 with fused softmax pass1 (writes scores + partMS)
    gemm_k1<<<dim3(512, 4), 512, 0, stream>>>(
        zbuf, V_w, 256, 0, V_b, partMS, scores);

    softmax_pass2<<<dim3(64, 8), 256, 0, stream>>>(scores, partMS, ctx, x_attn);

    gemm128<2, true><<<dim3(512, 6), 512, 0, stream>>>(
        ctx, w_ir, w_iz, w_in, 256, 0,
        cbias, cbias + 256, b_in, nullptr, nullptr, xgb);

    scan_gru<<<64, 512, 0, stream>>>(
        xgb, w_hr, w_hz, w_hn, b_hn, hidden, outputs, hlast);
}